// Round 12
// baseline (301.895 us; speedup 1.0000x reference)
//
#include <hip/hip_runtime.h>
#include <hip/hip_bf16.h>
#include <math.h>

// B=2,H=16 (BH=32), T=2048, D=64. fp32 in/out.
// d_out = [out (BH*T*64) | attn (BH*T*T)] fp32.
//
// R12: 512B-contiguous attn store runs (1KB/inst).
//  - block = 16 q-rows, 4 waves column-split: iteration = 128 cols, wave w
//    owns cols w*32. Shared P tile (16x128 f32, swizzled) -> store phase:
//    wave w stores rows w*4..w*4+3, each inst = 2 rows x 512B contiguous.
//  - pass A barrier-free: wave w rowsums its 512-col stripe from L2 (low
//    VGPR; no staging), one 256B psum LDS combine.
//  - pass B: K gll-staged (2 buf, stage-1-ahead at iter top), V direct
//    prefetch, stores youngest, tail vmcnt(6). nt stores (R11 A/B: nt wins).
//  - PV partials per wave (32-col K slice) -> one end-of-kernel LDS reduce.
//  - LDS 32KB kbuf + 8KB tbuf = 40960B -> 4 blocks/CU.

#define T_SEQ  2048
#define D_HEAD 64
#define BH_N   32
#define NIT    16            // 128-col iterations
#define OUT_ELEMS (BH_N * T_SEQ * D_HEAD)

typedef __attribute__((ext_vector_type(8))) short bf16x8;
typedef __attribute__((ext_vector_type(4))) float f32x4;

__device__ __forceinline__ unsigned short f2bf(float x) {
    __hip_bfloat16 h = __float2bfloat16(x);
    return *reinterpret_cast<unsigned short*>(&h);
}

// K-stage bank swizzle: XOR byte-bits 4-6 with (128B-row & 7); involution
__device__ __forceinline__ int swz(int o) { return o ^ (((o >> 7) & 7) << 4); }
// tbuf swizzle: 512B rows, XOR 16B-slot low bits with (row&7)
__device__ __forceinline__ int tswz(int row, int b) {
    return row * 512 + (b ^ ((row & 7) << 4));
}

// ---------------- precompute: rope tables ----------------
__global__ void rope_table_kernel(float* __restrict__ ctab, float* __restrict__ stab) {
    int i = blockIdx.x * blockDim.x + threadIdx.x;
    if (i >= T_SEQ * 32) return;
    int t = i >> 5;
    int j = i & 31;
    float invf = powf(10000.0f, -(float)j / 32.0f);
    float a = (float)t * invf;
    ctab[i] = cosf(a);
    stab[i] = sinf(a);
}

// ---------------- precompute: rope -> bf16 (q and k in one launch) ----------------
__global__ __launch_bounds__(256)
void ropebf16_kernel(const float* __restrict__ Q, const float* __restrict__ K,
                     const float* __restrict__ ctab, const float* __restrict__ stab,
                     unsigned short* __restrict__ Qb, unsigned short* __restrict__ Kb,
                     float qscale)
{
    const int r  = blockIdx.x * 16 + (threadIdx.x >> 4);
    const int c4 = threadIdx.x & 15;
    const int t  = r & (T_SEQ - 1);
    const float* X = blockIdx.y ? K : Q;
    unsigned short* H = blockIdx.y ? Kb : Qb;
    const float scale = blockIdx.y ? 1.0f : qscale;
    const float4* xr = (const float4*)(X + (size_t)r * 64);
    float4 a = xr[c4];
    float4 b = xr[c4 ^ 8];
    float4 c = ((const float4*)(ctab + t * 32))[c4 & 7];
    float4 s = ((const float4*)(stab + t * 32))[c4 & 7];
    float4 ro;
    if (c4 < 8) {
        ro.x = a.x * c.x - b.x * s.x; ro.y = a.y * c.y - b.y * s.y;
        ro.z = a.z * c.z - b.z * s.z; ro.w = a.w * c.w - b.w * s.w;
    } else {
        ro.x = a.x * c.x + b.x * s.x; ro.y = a.y * c.y + b.y * s.y;
        ro.z = a.z * c.z + b.z * s.z; ro.w = a.w * c.w + b.w * s.w;
    }
    ushort4 h;
    h.x = f2bf(ro.x * scale); h.y = f2bf(ro.y * scale);
    h.z = f2bf(ro.z * scale); h.w = f2bf(ro.w * scale);
    *(ushort4*)(H + (size_t)r * 64 + c4 * 4) = h;
}

// ---------------- precompute: V transpose -> bf16 [bh][64][T] ----------------
__global__ __launch_bounds__(256)
void vtbf16_kernel(const float* __restrict__ V, unsigned short* __restrict__ Vt)
{
    __shared__ float tile[64][65];
    const int bh = blockIdx.y;
    const int tt = blockIdx.x;
    const float* vg = V + ((size_t)bh * T_SEQ + tt * 64) * 64;
    #pragma unroll
    for (int i = 0; i < 4; ++i) {
        const int row = (threadIdx.x >> 4) + i * 16;
        const int c4  = threadIdx.x & 15;
        float4 a = *(const float4*)(vg + (size_t)row * 64 + c4 * 4);
        tile[row][c4 * 4 + 0] = a.x; tile[row][c4 * 4 + 1] = a.y;
        tile[row][c4 * 4 + 2] = a.z; tile[row][c4 * 4 + 3] = a.w;
    }
    __syncthreads();
    #pragma unroll
    for (int i = 0; i < 4; ++i) {
        const int d   = (threadIdx.x >> 4) + i * 16;
        const int tc4 = threadIdx.x & 15;
        ushort4 h;
        h.x = f2bf(tile[tc4 * 4 + 0][d]);
        h.y = f2bf(tile[tc4 * 4 + 1][d]);
        h.z = f2bf(tile[tc4 * 4 + 2][d]);
        h.w = f2bf(tile[tc4 * 4 + 3][d]);
        *(ushort4*)(Vt + ((size_t)bh * 64 + d) * T_SEQ + tt * 64 + tc4 * 4) = h;
    }
}

// ---------------- main attention kernel ----------------
__global__ __launch_bounds__(256, 4)
void attn_mfma_kernel(const unsigned short* __restrict__ Qb,
                      const unsigned short* __restrict__ Kb,
                      const unsigned short* __restrict__ Vt,
                      float* __restrict__ out, float* __restrict__ attn)
{
    __shared__ __align__(16) unsigned short kbuf[2][128][64];  // 32 KB
    __shared__ __align__(16) float tbuf[16][128];              // 8 KB (swizzled)

    const int tid  = threadIdx.x;
    const int lane = tid & 63;
    const int w    = tid >> 6;
    const int lrow = lane & 15;
    const int lgrp = lane >> 4;

    // XCD swizzle: 4096 blocks = 8 XCD * 512; 4 bh per XCD
    const int lid = blockIdx.x;
    const int vid = (lid & 7) * 512 + (lid >> 3);
    const int bh  = vid >> 7;
    const int m   = vid & 127;
    const int t0  = m * 16;               // block's 16 q-rows

    const size_t base = (size_t)bh * T_SEQ * D_HEAD;
    const char* kgb = (const char*)(Kb + base);                 // [2048][64] bf16
    const unsigned short* kgs = Kb + base;
    const unsigned short* vgb = Vt + (size_t)bh * 64 * T_SEQ;   // [64][2048] bf16

    // Q B-frags (col = lrow = q-row, k = lgrp*8..)
    bf16x8 qf0, qf1;
    {
        const unsigned short* qp = Qb + base + (size_t)(t0 + lrow) * 64 + lgrp * 8;
        qf0 = *(const bf16x8*)(qp);
        qf1 = *(const bf16x8*)(qp + 32);
    }

    // ===== pass A: rowsum, wave w covers cols [w*512, (w+1)*512), from L2 =====
    float rpa0 = 0.f, rpa1 = 0.f, rpa2 = 0.f, rpa3 = 0.f;
    for (int c = 0; c < 8; ++c) {
        const int col0 = w * 512 + c * 64;
        #pragma unroll
        for (int nt = 0; nt < 4; ++nt) {
            const unsigned short* kp = kgs + (size_t)(col0 + nt * 16 + lrow) * 64 + lgrp * 8;
            bf16x8 k0 = *(const bf16x8*)(kp);
            bf16x8 k1 = *(const bf16x8*)(kp + 32);
            f32x4 acc = (f32x4){0.f, 0.f, 0.f, 0.f};
            acc = __builtin_amdgcn_mfma_f32_16x16x32_bf16(k0, qf0, acc, 0, 0, 0);
            acc = __builtin_amdgcn_mfma_f32_16x16x32_bf16(k1, qf1, acc, 0, 0, 0);
            if (nt == 0) rpa0 += __builtin_amdgcn_exp2f(acc[0]) + __builtin_amdgcn_exp2f(acc[1])
                               + __builtin_amdgcn_exp2f(acc[2]) + __builtin_amdgcn_exp2f(acc[3]);
            if (nt == 1) rpa1 += __builtin_amdgcn_exp2f(acc[0]) + __builtin_amdgcn_exp2f(acc[1])
                               + __builtin_amdgcn_exp2f(acc[2]) + __builtin_amdgcn_exp2f(acc[3]);
            if (nt == 2) rpa2 += __builtin_amdgcn_exp2f(acc[0]) + __builtin_amdgcn_exp2f(acc[1])
                               + __builtin_amdgcn_exp2f(acc[2]) + __builtin_amdgcn_exp2f(acc[3]);
            if (nt == 3) rpa3 += __builtin_amdgcn_exp2f(acc[0]) + __builtin_amdgcn_exp2f(acc[1])
                               + __builtin_amdgcn_exp2f(acc[2]) + __builtin_amdgcn_exp2f(acc[3]);
        }
    }
    float rp = (rpa0 + rpa1) + (rpa2 + rpa3);
    rp += __shfl_xor(rp, 16, 64);
    rp += __shfl_xor(rp, 32, 64);          // wave-partial rowsum for q-row lrow
    {
        float* psum = &tbuf[0][0];         // [4][16] overlay
        if (lane < 16) psum[w * 16 + lrow] = rp;
    }
    __builtin_amdgcn_sched_barrier(0);
    __builtin_amdgcn_s_barrier();
    const float inv = 1.0f / (tbuf[0][0 + lrow] + tbuf[0][16 + lrow]
                            + tbuf[0][32 + lrow] + tbuf[0][48 + lrow]);
    __builtin_amdgcn_sched_barrier(0);
    __builtin_amdgcn_s_barrier();          // psum reads done before tbuf reuse

    // ===== pass B: attn + PV, 16 iterations of 128 cols =====
    char* klds = (char*)&kbuf[0][0][0];
    char* tlds = (char*)&tbuf[0][0];
    const int so0 = w * 4096 + lane * 16;
    const int sq0 = swz(so0);
    const int sq1 = swz(so0 + 1024);
    const int sq2 = swz(so0 + 2048);
    const int sq3 = swz(so0 + 3072);

#define STAGE_K(b, cc) do { \
    __builtin_amdgcn_global_load_lds((const unsigned int*)(kgb + (size_t)(cc) * 16384 + sq0), \
        (unsigned int*)(klds + (b) * 16384 + so0), 16, 0, 0); \
    __builtin_amdgcn_global_load_lds((const unsigned int*)(kgb + (size_t)(cc) * 16384 + sq1), \
        (unsigned int*)(klds + (b) * 16384 + so0 + 1024), 16, 0, 0); \
    __builtin_amdgcn_global_load_lds((const unsigned int*)(kgb + (size_t)(cc) * 16384 + sq2), \
        (unsigned int*)(klds + (b) * 16384 + so0 + 2048), 16, 0, 0); \
    __builtin_amdgcn_global_load_lds((const unsigned int*)(kgb + (size_t)(cc) * 16384 + sq3), \
        (unsigned int*)(klds + (b) * 16384 + so0 + 3072), 16, 0, 0); \
} while (0)

    f32x4 o4[4];
    #pragma unroll
    for (int nd = 0; nd < 4; ++nd) o4[nd] = (f32x4){0.f, 0.f, 0.f, 0.f};

    float* abase = attn + (size_t)bh * T_SEQ * T_SEQ;

    // prologue: stage chunk 0, prefetch V(0); force gll(0) done (V in flight)
    STAGE_K(0, 0);
    bf16x8 vf[4];
    #pragma unroll
    for (int nd = 0; nd < 4; ++nd)
        vf[nd] = *(const bf16x8*)(vgb + (size_t)(nd * 16 + lrow) * T_SEQ + w * 32 + lgrp * 8);
    asm volatile("s_waitcnt vmcnt(4)" ::: "memory");

    for (int cc = 0; cc < NIT; ++cc) {
        __builtin_amdgcn_s_barrier();          // barA: kbuf[cc&1] ready, tbuf free
        if (cc + 1 < NIT) STAGE_K((cc + 1) & 1, cc + 1);
        __builtin_amdgcn_sched_barrier(0);

        // QK^T on own 32-col slice: lane -> S[q=lrow][s = w*32 + nt*16 + lgrp*4 + j]
        const char* kb = klds + (cc & 1) * 16384;
        f32x4 s4[2];
        #pragma unroll
        for (int nt = 0; nt < 2; ++nt) {
            const int o = (w * 32 + nt * 16 + lrow) * 128 + lgrp * 16;
            bf16x8 a0 = *(const bf16x8*)(kb + swz(o));
            bf16x8 a1 = *(const bf16x8*)(kb + swz(o + 64));
            f32x4 acc = (f32x4){0.f, 0.f, 0.f, 0.f};
            acc = __builtin_amdgcn_mfma_f32_16x16x32_bf16(a0, qf0, acc, 0, 0, 0);
            acc = __builtin_amdgcn_mfma_f32_16x16x32_bf16(a1, qf1, acc, 0, 0, 0);
            s4[nt] = acc;
        }
        // normalized P via exp2 (Q pre-scaled by 0.125/ln2)
        #pragma unroll
        for (int nt = 0; nt < 2; ++nt) {
            s4[nt][0] = __builtin_amdgcn_exp2f(s4[nt][0]) * inv;
            s4[nt][1] = __builtin_amdgcn_exp2f(s4[nt][1]) * inv;
            s4[nt][2] = __builtin_amdgcn_exp2f(s4[nt][2]) * inv;
            s4[nt][3] = __builtin_amdgcn_exp2f(s4[nt][3]) * inv;
        }
        // P -> shared tbuf (swizzled): row lrow, cols w*32 + nt*16 + lgrp*4
        #pragma unroll
        for (int nt = 0; nt < 2; ++nt)
            *(f32x4*)(tlds + tswz(lrow, w * 128 + nt * 64 + lgrp * 16)) = s4[nt];
        asm volatile("s_waitcnt lgkmcnt(0)" ::: "memory");
        __builtin_amdgcn_sched_barrier(0);

        // PV on own slice: pa = P[lrow][w*32 + lgrp*8 .. +8]
        {
            const int b0 = w * 128 + lgrp * 32;
            f32x4 pa0 = *(const f32x4*)(tlds + tswz(lrow, b0));
            f32x4 pa1 = *(const f32x4*)(tlds + tswz(lrow, b0 + 16));
            bf16x8 pa;
            pa[0] = (short)f2bf(pa0[0]); pa[1] = (short)f2bf(pa0[1]);
            pa[2] = (short)f2bf(pa0[2]); pa[3] = (short)f2bf(pa0[3]);
            pa[4] = (short)f2bf(pa1[0]); pa[5] = (short)f2bf(pa1[1]);
            pa[6] = (short)f2bf(pa1[2]); pa[7] = (short)f2bf(pa1[3]);
            #pragma unroll
            for (int nd = 0; nd < 4; ++nd)
                o4[nd] = __builtin_amdgcn_mfma_f32_16x16x32_bf16(pa, vf[nd], o4[nd], 0, 0, 0);
        }
        __builtin_amdgcn_sched_barrier(0);
        __builtin_amdgcn_s_barrier();          // barB: all waves' tbuf written

        // transpose read-back: wave w owns rows w*4..w*4+3; 2 insts x 2 rows x 512B
        const int r0 = w * 4 + (lane >> 5);
        f32x4 tr0 = *(const f32x4*)(tlds + tswz(r0,     (lane & 31) * 16));
        f32x4 tr1 = *(const f32x4*)(tlds + tswz(r0 + 2, (lane & 31) * 16));
        asm volatile("s_waitcnt lgkmcnt(0)" ::: "memory");
        __builtin_amdgcn_sched_barrier(0);
        // V prefetch for cc+1 (WAR-safe: vf consumed by PV above)
        if (cc + 1 < NIT) {
            #pragma unroll
            for (int nd = 0; nd < 4; ++nd)
                vf[nd] = *(const bf16x8*)(vgb + (size_t)(nd * 16 + lrow) * T_SEQ
                                          + (cc + 1) * 128 + w * 32 + lgrp * 8);
        }
        __builtin_amdgcn_sched_barrier(0);
        // attn nt stores (youngest): 2 insts, each 2 rows x 512B contiguous
        __builtin_nontemporal_store(tr0,
            (f32x4*)(abase + (size_t)(t0 + r0) * T_SEQ + cc * 128 + (lane & 31) * 4));
        __builtin_nontemporal_store(tr1,
            (f32x4*)(abase + (size_t)(t0 + r0 + 2) * T_SEQ + cc * 128 + (lane & 31) * 4));
        __builtin_amdgcn_sched_barrier(0);
        // tail: force gll(cc+1) retired; allow [stores(cc)2 + V(cc+1)4] = 6
        if (cc + 1 < NIT) { asm volatile("s_waitcnt vmcnt(6)" ::: "memory"); }
    }

    // ===== cross-wave PV reduce (reuse kbuf as f32 scratch) =====
    __builtin_amdgcn_sched_barrier(0);
    __builtin_amdgcn_s_barrier();              // all kbuf/tbuf reads done
    float* pout = (float*)klds;                // [4][16][64] f32 = 16 KB
    #pragma unroll
    for (int nd = 0; nd < 4; ++nd)
        #pragma unroll
        for (int j = 0; j < 4; ++j)
            pout[w * 1024 + (lgrp * 4 + j) * 64 + nd * 16 + lrow] = o4[nd][j];
    asm volatile("s_waitcnt lgkmcnt(0)" ::: "memory");
    __builtin_amdgcn_sched_barrier(0);
    __builtin_amdgcn_s_barrier();
    {
        const int r  = tid >> 4;               // 0..15
        const int c4 = tid & 15;
        f32x4 a = (f32x4){0.f, 0.f, 0.f, 0.f};
        #pragma unroll
        for (int ww = 0; ww < 4; ++ww) {
            const f32x4 p = *(const f32x4*)(pout + ww * 1024 + r * 64 + c4 * 4);
            a.x += p.x; a.y += p.y; a.z += p.z; a.w += p.w;
        }
        __builtin_nontemporal_store(a,
            (f32x4*)(out + base + (size_t)(t0 + r) * D_HEAD + c4 * 4));
    }

#undef STAGE_K
}

extern "C" void kernel_launch(void* const* d_in, const int* in_sizes, int n_in,
                              void* d_out, int out_size, void* d_ws, size_t ws_size,
                              hipStream_t stream) {
    const float* q = (const float*)d_in[0];
    const float* k = (const float*)d_in[1];
    const float* v = (const float*)d_in[2];
    float* out  = (float*)d_out;
    float* attn = out + (size_t)OUT_ELEMS;

    float* ctab = (float*)d_ws;                              // T*32 f32
    float* stab = ctab + T_SEQ * 32;                         // T*32 f32
    unsigned short* wsu = (unsigned short*)(stab + T_SEQ * 32);
    const size_t NE = (size_t)BH_N * T_SEQ * D_HEAD;         // 4,194,304
    unsigned short* Qb = wsu + 0 * NE;
    unsigned short* Kb = wsu + 1 * NE;
    unsigned short* Vt = wsu + 2 * NE;                       // ~25.7 MB total

    const float QSCALE = 0.18033688011112042f;               // 0.125 / ln(2)

    rope_table_kernel<<<dim3((T_SEQ * 32 + 255) / 256), dim3(256), 0, stream>>>(ctab, stab);
    ropebf16_kernel<<<dim3(BH_N * T_SEQ / 16, 2), dim3(256), 0, stream>>>(q, k, ctab, stab, Qb, Kb, QSCALE);
    vtbf16_kernel<<<dim3(T_SEQ / 64, BH_N), dim3(256), 0, stream>>>(v, Vt);
    attn_mfma_kernel<<<dim3(BH_N * T_SEQ / 16), dim3(256), 0, stream>>>(Qb, Kb, Vt, out, attn);
}

// Round 14
// 183.432 us; speedup vs baseline: 1.6458x; 1.6458x over previous
//
#include <hip/hip_runtime.h>
#include <hip/hip_bf16.h>
#include <math.h>

// B=2,H=16 (BH=32), T=2048, D=64. fp32 in/out.
// d_out = [out (BH*T*64) | attn (BH*T*T)] fp32.
//
// R14 = exact revert to R9 (183.5 us champion).
//  - two-pass, 64-row blocks (4 waves x 16 rows), 32 chunks of 64 cols.
//  - K triple-buffer gll staging (pre-swizzled source, linear LDS dest,
//    swizzled read); V^T direct-to-reg prefetch; exp2 softmax (Q pre-scaled
//    by 0.125/ln2); in-LDS f32 P transpose -> 256B-contiguous nt attn store
//    runs; stores-youngest + counted tail vmcnt(18)/(16).
//  - nt stores required (R11 A/B: plain loses 44 us via L2 pollution).
//  - LDS 24KB kbuf + 16KB tbuf = 40KB -> 4 blocks/CU at 256 threads.

#define T_SEQ  2048
#define D_HEAD 64
#define BH_N   32
#define NCH    32            // 64-col chunks
#define OUT_ELEMS (BH_N * T_SEQ * D_HEAD)

typedef __attribute__((ext_vector_type(8))) short bf16x8;
typedef __attribute__((ext_vector_type(4))) float f32x4;

__device__ __forceinline__ unsigned short f2bf(float x) {
    __hip_bfloat16 h = __float2bfloat16(x);
    return *reinterpret_cast<unsigned short*>(&h);
}

// K-stage bank swizzle: XOR byte-bits 4-6 with (128B-row & 7); involution
__device__ __forceinline__ int swz(int o) { return o ^ (((o >> 7) & 7) << 4); }
// tbuf swizzle: row stride 256B, XOR 16B-slot with (row&7)
__device__ __forceinline__ int tswz(int row, int bcol) {
    return row * 256 + (bcol ^ ((row & 7) << 4));
}

// ---------------- precompute: rope tables ----------------
__global__ void rope_table_kernel(float* __restrict__ ctab, float* __restrict__ stab) {
    int i = blockIdx.x * blockDim.x + threadIdx.x;
    if (i >= T_SEQ * 32) return;
    int t = i >> 5;
    int j = i & 31;
    float invf = powf(10000.0f, -(float)j / 32.0f);
    float a = (float)t * invf;
    ctab[i] = cosf(a);
    stab[i] = sinf(a);
}

// ---------------- precompute: rope -> bf16 (q and k in one launch) ----------------
__global__ __launch_bounds__(256)
void ropebf16_kernel(const float* __restrict__ Q, const float* __restrict__ K,
                     const float* __restrict__ ctab, const float* __restrict__ stab,
                     unsigned short* __restrict__ Qb, unsigned short* __restrict__ Kb,
                     float qscale)
{
    const int r  = blockIdx.x * 16 + (threadIdx.x >> 4);
    const int c4 = threadIdx.x & 15;
    const int t  = r & (T_SEQ - 1);
    const float* X = blockIdx.y ? K : Q;
    unsigned short* H = blockIdx.y ? Kb : Qb;
    const float scale = blockIdx.y ? 1.0f : qscale;
    const float4* xr = (const float4*)(X + (size_t)r * 64);
    float4 a = xr[c4];
    float4 b = xr[c4 ^ 8];
    float4 c = ((const float4*)(ctab + t * 32))[c4 & 7];
    float4 s = ((const float4*)(stab + t * 32))[c4 & 7];
    float4 ro;
    if (c4 < 8) {
        ro.x = a.x * c.x - b.x * s.x; ro.y = a.y * c.y - b.y * s.y;
        ro.z = a.z * c.z - b.z * s.z; ro.w = a.w * c.w - b.w * s.w;
    } else {
        ro.x = a.x * c.x + b.x * s.x; ro.y = a.y * c.y + b.y * s.y;
        ro.z = a.z * c.z + b.z * s.z; ro.w = a.w * c.w + b.w * s.w;
    }
    ushort4 h;
    h.x = f2bf(ro.x * scale); h.y = f2bf(ro.y * scale);
    h.z = f2bf(ro.z * scale); h.w = f2bf(ro.w * scale);
    *(ushort4*)(H + (size_t)r * 64 + c4 * 4) = h;
}

// ---------------- precompute: V transpose -> bf16 [bh][64][T] ----------------
__global__ __launch_bounds__(256)
void vtbf16_kernel(const float* __restrict__ V, unsigned short* __restrict__ Vt)
{
    __shared__ float tile[64][65];
    const int bh = blockIdx.y;
    const int tt = blockIdx.x;
    const float* vg = V + ((size_t)bh * T_SEQ + tt * 64) * 64;
    #pragma unroll
    for (int i = 0; i < 4; ++i) {
        const int row = (threadIdx.x >> 4) + i * 16;
        const int c4  = threadIdx.x & 15;
        float4 a = *(const float4*)(vg + (size_t)row * 64 + c4 * 4);
        tile[row][c4 * 4 + 0] = a.x; tile[row][c4 * 4 + 1] = a.y;
        tile[row][c4 * 4 + 2] = a.z; tile[row][c4 * 4 + 3] = a.w;
    }
    __syncthreads();
    #pragma unroll
    for (int i = 0; i < 4; ++i) {
        const int d   = (threadIdx.x >> 4) + i * 16;
        const int tc4 = threadIdx.x & 15;
        ushort4 h;
        h.x = f2bf(tile[tc4 * 4 + 0][d]);
        h.y = f2bf(tile[tc4 * 4 + 1][d]);
        h.z = f2bf(tile[tc4 * 4 + 2][d]);
        h.w = f2bf(tile[tc4 * 4 + 3][d]);
        *(ushort4*)(Vt + ((size_t)bh * 64 + d) * T_SEQ + tt * 64 + tc4 * 4) = h;
    }
}

// ---------------- main attention kernel ----------------
__global__ __launch_bounds__(256, 4)
void attn_mfma_kernel(const unsigned short* __restrict__ Qb,
                      const unsigned short* __restrict__ Kb,
                      const unsigned short* __restrict__ Vt,
                      float* __restrict__ out, float* __restrict__ attn)
{
    __shared__ __align__(16) unsigned short kbuf[3][64][64];   // 24 KB
    __shared__ __align__(16) float tbuf[4][16 * 64];           // 16 KB (swizzled)

    const int tid  = threadIdx.x;
    const int lane = tid & 63;
    const int w    = tid >> 6;
    const int lrow = lane & 15;
    const int lgrp = lane >> 4;

    // XCD swizzle: 1024 blocks = 8 XCD * 128; 4 bh per XCD
    const int lid = blockIdx.x;
    const int vid = (lid & 7) * 128 + (lid >> 3);
    const int bh  = vid >> 5;
    const int m   = vid & 31;
    const int t0  = m * 64 + w * 16;       // this wave's first q-row

    const size_t base = (size_t)bh * T_SEQ * D_HEAD;
    const char* kgb = (const char*)(Kb + base);                 // [2048][64] bf16
    const unsigned short* vgb = Vt + (size_t)bh * 64 * T_SEQ;   // [64][2048] bf16

    // Q B-frags (col = lrow = q-row, k = lgrp*8..)
    bf16x8 qf0, qf1;
    {
        const unsigned short* qp = Qb + base + (size_t)(t0 + lrow) * 64 + lgrp * 8;
        qf0 = *(const bf16x8*)(qp);
        qf1 = *(const bf16x8*)(qp + 32);
    }

    const int so0 = w * 1024 + lane * 16;
    const int so1 = so0 + 4096;
    const int sq0 = swz(so0);
    const int sq1 = swz(so1);
    char* klds = (char*)&kbuf[0][0][0];
    char* tlds = (char*)&tbuf[w][0];

#define STAGE_K(b, cc) do { \
    __builtin_amdgcn_global_load_lds((const unsigned int*)(kgb + (size_t)(cc) * 8192 + sq0), \
        (unsigned int*)(klds + (b) * 8192 + w * 1024), 16, 0, 0); \
    __builtin_amdgcn_global_load_lds((const unsigned int*)(kgb + (size_t)(cc) * 8192 + sq1), \
        (unsigned int*)(klds + (b) * 8192 + 4096 + w * 1024), 16, 0, 0); \
} while (0)

    // ================= pass A: rowsum =================
    float rpa0 = 0.f, rpa1 = 0.f, rpa2 = 0.f, rpa3 = 0.f;
    STAGE_K(0, 0);
    STAGE_K(1, 1);
    for (int cc = 0; cc < NCH; ++cc) {
        if (cc < NCH - 1) { asm volatile("s_waitcnt vmcnt(2)" ::: "memory"); }
        else              { asm volatile("s_waitcnt vmcnt(0)" ::: "memory"); }
        __builtin_amdgcn_s_barrier();
        if (cc + 2 < NCH) STAGE_K((cc + 2) % 3, cc + 2);
        __builtin_amdgcn_sched_barrier(0);
        const char* kb = klds + (cc % 3) * 8192;
        #pragma unroll
        for (int nt = 0; nt < 4; ++nt) {
            const int o = (nt * 16 + lrow) * 128 + lgrp * 16;
            bf16x8 a0 = *(const bf16x8*)(kb + swz(o));
            bf16x8 a1 = *(const bf16x8*)(kb + swz(o + 64));
            f32x4 acc = (f32x4){0.f, 0.f, 0.f, 0.f};
            acc = __builtin_amdgcn_mfma_f32_16x16x32_bf16(a0, qf0, acc, 0, 0, 0);
            acc = __builtin_amdgcn_mfma_f32_16x16x32_bf16(a1, qf1, acc, 0, 0, 0);
            rpa0 += __builtin_amdgcn_exp2f(acc[0]);
            rpa1 += __builtin_amdgcn_exp2f(acc[1]);
            rpa2 += __builtin_amdgcn_exp2f(acc[2]);
            rpa3 += __builtin_amdgcn_exp2f(acc[3]);
        }
    }
    float rp = (rpa0 + rpa1) + (rpa2 + rpa3);
    rp += __shfl_xor(rp, 16, 64);
    rp += __shfl_xor(rp, 32, 64);
    const float inv = 1.0f / rp;

    // inter-pass barrier
    __builtin_amdgcn_sched_barrier(0);
    __builtin_amdgcn_s_barrier();

    // ================= pass B: attn + PV =================
    f32x4 o4[4];
    #pragma unroll
    for (int nd = 0; nd < 4; ++nd) o4[nd] = (f32x4){0.f, 0.f, 0.f, 0.f};

    float* abase = attn + (size_t)bh * T_SEQ * T_SEQ;

    // prologue: K stages then V(0); force gll(0) done (allow gll(1)+V(0)=10)
    STAGE_K(0, 0);
    STAGE_K(1, 1);
    bf16x8 vf[8];
    #pragma unroll
    for (int nd = 0; nd < 4; ++nd)
        #pragma unroll
        for (int ks = 0; ks < 2; ++ks)
            vf[nd * 2 + ks] = *(const bf16x8*)(vgb + (size_t)(nd * 16 + lrow) * T_SEQ
                                               + ks * 32 + lgrp * 8);
    asm volatile("s_waitcnt vmcnt(10)" ::: "memory");

    for (int cc = 0; cc < NCH; ++cc) {
        __builtin_amdgcn_s_barrier();
        __builtin_amdgcn_sched_barrier(0);

        // QK^T from staged K: lane -> S[q=lrow][s = nt*16 + lgrp*4 + j]
        const char* kb = klds + (cc % 3) * 8192;
        f32x4 s4[4];
        #pragma unroll
        for (int nt = 0; nt < 4; ++nt) {
            const int o = (nt * 16 + lrow) * 128 + lgrp * 16;
            bf16x8 a0 = *(const bf16x8*)(kb + swz(o));
            bf16x8 a1 = *(const bf16x8*)(kb + swz(o + 64));
            f32x4 acc = (f32x4){0.f, 0.f, 0.f, 0.f};
            acc = __builtin_amdgcn_mfma_f32_16x16x32_bf16(a0, qf0, acc, 0, 0, 0);
            acc = __builtin_amdgcn_mfma_f32_16x16x32_bf16(a1, qf1, acc, 0, 0, 0);
            s4[nt] = acc;
        }
        // normalized P via exp2 (Q pre-scaled by 0.125/ln2)
        #pragma unroll
        for (int nt = 0; nt < 4; ++nt) {
            s4[nt][0] = __builtin_amdgcn_exp2f(s4[nt][0]) * inv;
            s4[nt][1] = __builtin_amdgcn_exp2f(s4[nt][1]) * inv;
            s4[nt][2] = __builtin_amdgcn_exp2f(s4[nt][2]) * inv;
            s4[nt][3] = __builtin_amdgcn_exp2f(s4[nt][3]) * inv;
        }
        // P f32 -> tbuf (swizzled); serves PV A-frags AND store transpose
        #pragma unroll
        for (int nt = 0; nt < 4; ++nt)
            *(f32x4*)(tlds + tswz(lrow, (nt * 16 + lgrp * 4) * 4)) = s4[nt];
        asm volatile("s_waitcnt lgkmcnt(0)" ::: "memory");
        __builtin_amdgcn_sched_barrier(0);

        // PV A-frags: read 8 f32 per ks from tbuf, cvt to bf16x8
        #pragma unroll
        for (int ks = 0; ks < 2; ++ks) {
            f32x4 pa0 = *(const f32x4*)(tlds + tswz(lrow, (ks * 32 + lgrp * 8) * 4));
            f32x4 pa1 = *(const f32x4*)(tlds + tswz(lrow, (ks * 32 + lgrp * 8 + 4) * 4));
            bf16x8 pa;
            pa[0] = (short)f2bf(pa0[0]); pa[1] = (short)f2bf(pa0[1]);
            pa[2] = (short)f2bf(pa0[2]); pa[3] = (short)f2bf(pa0[3]);
            pa[4] = (short)f2bf(pa1[0]); pa[5] = (short)f2bf(pa1[1]);
            pa[6] = (short)f2bf(pa1[2]); pa[7] = (short)f2bf(pa1[3]);
            #pragma unroll
            for (int nd = 0; nd < 4; ++nd)
                o4[nd] = __builtin_amdgcn_mfma_f32_16x16x32_bf16(pa, vf[nd * 2 + ks], o4[nd], 0, 0, 0);
        }
        // transpose read-back: inst i covers rows 4i..4i+3, 256B contiguous/row
        f32x4 tr[4];
        #pragma unroll
        for (int i = 0; i < 4; ++i)
            tr[i] = *(const f32x4*)(tlds + tswz(i * 4 + (lane >> 4), (lane & 15) * 16));
        __builtin_amdgcn_sched_barrier(0);
        // V loads for cc+1 (WAR-safe), then K stage, then stores (youngest)
        if (cc + 1 < NCH) {
            #pragma unroll
            for (int nd = 0; nd < 4; ++nd)
                #pragma unroll
                for (int ks = 0; ks < 2; ++ks)
                    vf[nd * 2 + ks] = *(const bf16x8*)(vgb + (size_t)(nd * 16 + lrow) * T_SEQ
                                                       + (cc + 1) * 64 + ks * 32 + lgrp * 8);
        }
        if (cc + 2 < NCH) STAGE_K((cc + 2) % 3, cc + 2);
        __builtin_amdgcn_sched_barrier(0);
        // attn stores: 4 insts, each 4 rows x 256B contiguous
        #pragma unroll
        for (int i = 0; i < 4; ++i)
            __builtin_nontemporal_store(tr[i],
                (f32x4*)(abase + (size_t)(t0 + i * 4 + (lane >> 4)) * T_SEQ
                         + cc * 64 + (lane & 15) * 4));
        __builtin_amdgcn_sched_barrier(0);
        // tail: force gll(cc+1); allow [stores(cc)4 + STAGE(cc+2)2 + V(cc+1)8
        // + stores(cc-1)4] = 18 youngest in flight
        if (cc < NCH - 2)      { asm volatile("s_waitcnt vmcnt(18)" ::: "memory"); }
        else if (cc < NCH - 1) { asm volatile("s_waitcnt vmcnt(16)" ::: "memory"); }
    }

    // out store: lane holds out[t0 + lgrp*4 + j][nd*16 + lrow] (normalized)
    #pragma unroll
    for (int nd = 0; nd < 4; ++nd)
        #pragma unroll
        for (int j = 0; j < 4; ++j)
            __builtin_nontemporal_store(o4[nd][j],
                out + base + (size_t)(t0 + lgrp * 4 + j) * D_HEAD + nd * 16 + lrow);

#undef STAGE_K
}

extern "C" void kernel_launch(void* const* d_in, const int* in_sizes, int n_in,
                              void* d_out, int out_size, void* d_ws, size_t ws_size,
                              hipStream_t stream) {
    const float* q = (const float*)d_in[0];
    const float* k = (const float*)d_in[1];
    const float* v = (const float*)d_in[2];
    float* out  = (float*)d_out;
    float* attn = out + (size_t)OUT_ELEMS;

    float* ctab = (float*)d_ws;                              // T*32 f32
    float* stab = ctab + T_SEQ * 32;                         // T*32 f32
    unsigned short* wsu = (unsigned short*)(stab + T_SEQ * 32);
    const size_t NE = (size_t)BH_N * T_SEQ * D_HEAD;         // 4,194,304
    unsigned short* Qb = wsu + 0 * NE;
    unsigned short* Kb = wsu + 1 * NE;
    unsigned short* Vt = wsu + 2 * NE;                       // ~25.7 MB total

    const float QSCALE = 0.18033688011112042f;               // 0.125 / ln(2)

    rope_table_kernel<<<dim3((T_SEQ * 32 + 255) / 256), dim3(256), 0, stream>>>(ctab, stab);
    ropebf16_kernel<<<dim3(BH_N * T_SEQ / 16, 2), dim3(256), 0, stream>>>(q, k, ctab, stab, Qb, Kb, QSCALE);
    vtbf16_kernel<<<dim3(T_SEQ / 64, BH_N), dim3(256), 0, stream>>>(v, Vt);
    attn_mfma_kernel<<<dim3(BH_N * T_SEQ / 64), dim3(256), 0, stream>>>(Qb, Kb, Vt, out, attn);
}